// Round 4
// baseline (88.065 us; speedup 1.0000x reference)
//
#include <hip/hip_runtime.h>
#include <math.h>

#define B 32
#define G 32
#define P 8400
#define NC 80
#define NCAND 27
#define INFF 3.4e38f
#define MWPI 264   // mask words per image (264*32 = 8448 bits >= 8400), padded so
                   // no mask word is shared between images (avoids cross-block races)

__device__ __forceinline__ float iou_prior(float gx1, float gy1, float gx2, float gy2, float4 pr) {
    // Matches reference overlaps: union = max(area_g + area_p - inter, 1e-6)
    float ltx = fmaxf(gx1, pr.x), lty = fmaxf(gy1, pr.y);
    float rbx = fminf(gx2, pr.z), rby = fminf(gy2, pr.w);
    float w = fmaxf(rbx - ltx, 0.f), h = fmaxf(rby - lty, 0.f);
    float inter = w * h;
    float ag = (gx2 - gx1) * (gy2 - gy1);
    float ap = (pr.z - pr.x) * (pr.w - pr.y);
    float uni = fmaxf(ag + ap - inter, 1e-6f);
    return inter / uni;
}

// ---- K1: one block per image. 16 waves x 2 gts candidate selection (validated
// 7x7 analytic window), then block-wide count + multi-assign resolve.
// Writes rec[] only at positive priors; sets a per-image bitmask for K2.
__global__ __launch_bounds__(1024) void k_assign(const float4* __restrict__ priors,
                                                 const float4* __restrict__ gtb,
                                                 const float4* __restrict__ predb,
                                                 const int* __restrict__ gtl,
                                                 const float* __restrict__ flagv,
                                                 float4* __restrict__ rec,
                                                 unsigned int* __restrict__ mask) {
    __shared__ int   cnt[P];            // 33.6 KB
    __shared__ int   s_ci[G * NCAND];   // candidate prior index
    __shared__ float s_cp[G * NCAND];   // candidate positive flag
    const int b = blockIdx.x;
    const int t = threadIdx.x;
    const int wave = t >> 6, lane = t & 63;

    for (int i = t; i < P; i += 1024) cnt[i] = 0;
    if (t < MWPI) mask[b * MWPI + t] = 0u;

    const int   starts[3] = {0, 6400, 8000};
    const int   fsz[3]    = {80, 40, 20};
    const float inv[3]    = {0.125f, 0.0625f, 0.03125f};   // exact pow2 -> exact floor
    const int c7 = lane % 7, r7 = lane / 7;

    for (int g = wave; g < G; g += 16) {
        const int bg = b * G + g;
        if (flagv[bg] <= 0.f) {
            // padded gt: no positives possible
            if (lane < NCAND) { s_ci[g * NCAND + lane] = 0; s_cp[g * NCAND + lane] = 0.f; }
            continue;
        }
        float4 gt = gtb[bg];
        float gcx = (gt.x + gt.z) * 0.5f, gcy = (gt.y + gt.w) * 0.5f;

        for (int l = 0; l < 3; ++l) {
            int fs = fsz[l];
            int x0 = (int)(gcx * inv[l]);
            int y0 = (int)(gcy * inv[l]);
            int xs = min(max(x0 - 3, 0), fs - 7);
            int ys = min(max(y0 - 3, 0), fs - 7);

            float v = INFF; int pi = 0x7fffffff;
            if (lane < 49) {
                int col = xs + c7, row = ys + r7;
                pi = starts[l] + row * fs + col;
                float4 pr = priors[pi];
                // identical float expression to the validated version
                float dx = gcx - (pr.x + pr.z) * 0.5f;
                float dy = gcy - (pr.y + pr.w) * 0.5f;
                v = sqrtf(dx * dx + dy * dy);
            }
            // rank among the 49 window candidates, (val,idx) lexicographic
            int rank = 0;
            for (int j = 0; j < 49; ++j) {          // uniform j -> v_readlane
                float ov = __shfl(v, j, 64);
                int   oi = __shfl(pi, j, 64);
                rank += (ov < v || (ov == v && oi < pi)) ? 1 : 0;
            }
            if (lane < 49 && rank < 9) s_ci[g * NCAND + l * 9 + rank] = pi;
            // same-wave LDS RAW below: safe without __syncthreads
        }

        float covv = 0.f; int cingv = 0;
        if (lane < NCAND) {
            int myIdx = s_ci[g * NCAND + lane];
            float4 pr = priors[myIdx];
            covv = iou_prior(gt.x, gt.y, gt.z, gt.w, pr);
            float pcx = (pr.x + pr.z) * 0.5f, pcy = (pr.y + pr.w) * 0.5f;
            float m = fminf(fminf(pcx - gt.x, pcy - gt.y), fminf(gt.z - pcx, gt.w - pcy));
            cingv = (m > 1e-9f) ? 1 : 0;
        }
        // serial-order reductions (same summation order as the validated version)
        float s = 0.f;
        for (int j = 0; j < NCAND; ++j) s += __shfl(covv, j, 64);
        float mean = s / (float)NCAND;
        float d = covv - mean;
        float d2 = (lane < NCAND) ? d * d : 0.f;
        float vs = 0.f;
        for (int j = 0; j < NCAND; ++j) vs += __shfl(d2, j, 64);
        float thr = mean + sqrtf(vs / (float)(NCAND - 1));   // ddof=1

        if (lane < NCAND) s_cp[g * NCAND + lane] = (covv > thr && cingv) ? 1.f : 0.f;
    }
    __syncthreads();

    const bool active = (t < G * NCAND) && (s_cp[t] > 0.f);
    int p = 0;
    if (active) { p = s_ci[t]; atomicAdd(&cnt[p], 1); }
    __syncthreads();

    if (active) {
        int gi = t / NCAND;
        if (cnt[p] > 1) {
            // multi-assigned: argmax over ALL g of IoU(gt, prior[p]), tie -> first
            float4 pr = priors[p];
            float best = -1.f; gi = 0;
            for (int g2 = 0; g2 < G; ++g2) {
                float4 gt2 = gtb[b * G + g2];
                float ov = iou_prior(gt2.x, gt2.y, gt2.z, gt2.w, pr);
                if (ov > best) { best = ov; gi = g2; }
            }
            // duplicates at same p compute identical gi -> identical record (benign)
        }
        float4 gt = gtb[b * G + gi];
        float4 pd = predb[b * P + p];
        // reference stage-7 IoU: clipped areas, +1e-9 in denominator
        float ltx = fmaxf(gt.x, pd.x), lty = fmaxf(gt.y, pd.y);
        float rbx = fminf(gt.z, pd.z), rby = fminf(gt.w, pd.w);
        float iw = fmaxf(rbx - ltx, 0.f), ih = fmaxf(rby - lty, 0.f);
        float inter = iw * ih;
        float ag = fmaxf(gt.z - gt.x, 0.f) * fmaxf(gt.w - gt.y, 0.f);
        float ap = fmaxf(pd.z - pd.x, 0.f) * fmaxf(pd.w - pd.y, 0.f);
        float iou = inter / (ag + ap - inter + 1e-9f);
        int lab = gtl[b * G + gi];
        rec[b * P + p] = make_float4(1.f, (float)gi, iou, (float)lab);
        atomicOr(&mask[b * MWPI + (p >> 5)], 1u << (p & 31));
    }
}

// ---- K2: fused dense outputs: scores (float4-coalesced) + labels/boxes/fgm -
__global__ __launch_bounds__(256) void k_out(const float4* __restrict__ rec,
                                             const unsigned int* __restrict__ mask,
                                             const float4* __restrict__ gtb,
                                             float* __restrict__ labels,
                                             float4* __restrict__ boxes,
                                             float4* __restrict__ scores,
                                             float* __restrict__ fgm) {
    int tid = blockIdx.x * 256 + threadIdx.x;   // over B*P*20, exact grid
    int bp = tid / 20;
    int q = tid - bp * 20;
    int b = bp / P;
    int p = bp - b * P;
    bool fg = (mask[b * MWPI + (p >> 5)] >> (p & 31)) & 1u;
    float4 r = make_float4(0.f, 0.f, 0.f, 0.f);
    float4 o = make_float4(0.f, 0.f, 0.f, 0.f);
    if (fg) {
        r = rec[bp];
        int lab = (int)r.w;
        int c0 = q * 4;
        if (lab >= c0 && lab < c0 + 4) {
            (&o.x)[lab - c0] = r.z;
        }
    }
    scores[tid] = o;
    if (q == 0) {
        int gi = fg ? (int)r.y : 0;             // background: argmax(all-zero) = 0
        labels[bp] = fg ? r.w : (float)NC;
        boxes[bp] = gtb[b * G + gi];
        fgm[bp] = fg ? 1.f : 0.f;
    }
}

extern "C" void kernel_launch(void* const* d_in, const int* in_sizes, int n_in,
                              void* d_out, int out_size, void* d_ws, size_t ws_size,
                              hipStream_t stream) {
    const float4* priors = (const float4*)d_in[0];
    // d_in[1] = num_level_priors (compile-time constants here)
    const int*    gtl    = (const int*)d_in[2];
    const float4* gtb    = (const float4*)d_in[3];
    const float*  flagv  = (const float*)d_in[4];
    const float4* predb  = (const float4*)d_in[5];

    char* wsb = (char*)d_ws;
    float4*       rec  = (float4*)wsb;                          // B*P*16 B
    unsigned int* mask = (unsigned int*)(wsb + (size_t)B * P * 16);  // B*MWPI*4 B

    float*  out    = (float*)d_out;
    float*  labels = out;                                  // B*P
    float4* boxes  = (float4*)(out + B * P);               // B*P*4
    float4* scores = (float4*)(out + B * P + B * P * 4);   // B*P*80
    float*  fgm    = out + B * P + B * P * 4 + B * P * NC; // B*P

    hipLaunchKernelGGL(k_assign, dim3(B),                dim3(1024), 0, stream,
                       priors, gtb, predb, gtl, flagv, rec, mask);
    hipLaunchKernelGGL(k_out,    dim3(B * P * 20 / 256), dim3(256),  0, stream,
                       rec, mask, gtb, labels, boxes, scores, fgm);
}

// Round 5
// 70.015 us; speedup vs baseline: 1.2578x; 1.2578x over previous
//
#include <hip/hip_runtime.h>
#include <math.h>

#define B 32
#define G 32
#define P 8400
#define NC 80
#define NCAND 27
#define INFF 3.4e38f

__device__ __forceinline__ float iou_prior(float gx1, float gy1, float gx2, float gy2, float4 pr) {
    // Matches reference overlaps: union = max(area_g + area_p - inter, 1e-6)
    float ltx = fmaxf(gx1, pr.x), lty = fmaxf(gy1, pr.y);
    float rbx = fminf(gx2, pr.z), rby = fminf(gy2, pr.w);
    float w = fmaxf(rbx - ltx, 0.f), h = fmaxf(rby - lty, 0.f);
    float inter = w * h;
    float ag = (gx2 - gx1) * (gy2 - gy1);
    float ap = (pr.z - pr.x) * (pr.w - pr.y);
    float uni = fmaxf(ag + ap - inter, 1e-6f);
    return inter / uni;
}

// ---- K1: analytic top-9 per level. One wave per (b,g). ---------------------
// Priors are the fixed (x+0.5)*stride meshgrid; the 9 nearest grid points to
// an interior query lie within a 7x7 window around its cell. gt centers in
// [40,600] are always >=4 cells interior on every level. Rank-select by
// (dist, idx) lexicographic == lax.top_k stable order.
// Also grid-stride zeroes rec[] (consumed by k_resolve / k_out).
__global__ __launch_bounds__(64) void k_cand(const float4* __restrict__ priors,
                                             const float4* __restrict__ gtb,
                                             const float* __restrict__ flagv,
                                             int* __restrict__ cand_idx,
                                             float* __restrict__ cand_pos,
                                             float4* __restrict__ rec) {
    __shared__ int cslot[NCAND];
    const int bg = blockIdx.x;
    const int lane = threadIdx.x;

    // fused rec zeroing at full-grid parallelism (before any early return)
    for (int i = bg * 64 + lane; i < B * P; i += B * G * 64)
        rec[i] = make_float4(0.f, 0.f, 0.f, 0.f);

    if (flagv[bg] <= 0.f) {
        // padded gt: is_in_candidate all-zero -> no positives possible
        if (lane < NCAND) { cand_idx[bg * NCAND + lane] = 0; cand_pos[bg * NCAND + lane] = 0.f; }
        return;
    }

    float4 gt = gtb[bg];
    float gcx = (gt.x + gt.z) * 0.5f, gcy = (gt.y + gt.w) * 0.5f;

    const int   starts[3] = {0, 6400, 8000};
    const int   fsz[3]    = {80, 40, 20};
    const float inv[3]    = {0.125f, 0.0625f, 0.03125f};   // exact pow2 -> exact floor

    const int c7 = lane % 7, r7 = lane / 7;

    for (int l = 0; l < 3; ++l) {
        int fs = fsz[l];
        int x0 = (int)(gcx * inv[l]);          // cell containing query (exact)
        int y0 = (int)(gcy * inv[l]);
        int xs = min(max(x0 - 3, 0), fs - 7);
        int ys = min(max(y0 - 3, 0), fs - 7);

        float v = INFF; int pi = 0x7fffffff;
        if (lane < 49) {
            int col = xs + c7, row = ys + r7;
            pi = starts[l] + row * fs + col;
            float4 pr = priors[pi];
            // identical float expression to the validated scan version
            float dx = gcx - (pr.x + pr.z) * 0.5f;
            float dy = gcy - (pr.y + pr.w) * 0.5f;
            v = sqrtf(dx * dx + dy * dy);
        }
        // rank among the 49 window candidates, (val,idx) lexicographic
        int rank = 0;
        for (int j = 0; j < 49; ++j) {          // uniform j -> v_readlane
            float ov = __shfl(v, j, 64);
            int   oi = __shfl(pi, j, 64);
            rank += (ov < v || (ov == v && oi < pi)) ? 1 : 0;
        }
        if (lane < 49 && rank < 9) cslot[l * 9 + rank] = pi;
    }
    __syncthreads();

    // overlaps + center-in-gt at the 27 candidates (lane r holds candidate r)
    float covv = 0.f; int cingv = 0; int myIdx = 0;
    if (lane < NCAND) {
        myIdx = cslot[lane];
        float4 pr = priors[myIdx];
        covv = iou_prior(gt.x, gt.y, gt.z, gt.w, pr);
        float pcx = (pr.x + pr.z) * 0.5f, pcy = (pr.y + pr.w) * 0.5f;
        float m = fminf(fminf(pcx - gt.x, pcy - gt.y), fminf(gt.z - pcx, gt.w - pcy));
        cingv = (m > 1e-9f) ? 1 : 0;
    }
    // serial-order reductions (same summation order as the validated version)
    float s = 0.f;
    for (int j = 0; j < NCAND; ++j) s += __shfl(covv, j, 64);
    float mean = s / (float)NCAND;
    float d = covv - mean;
    float d2 = (lane < NCAND) ? d * d : 0.f;
    float vs = 0.f;
    for (int j = 0; j < NCAND; ++j) vs += __shfl(d2, j, 64);
    float thr = mean + sqrtf(vs / (float)(NCAND - 1));   // ddof=1

    if (lane < NCAND) {
        cand_idx[bg * NCAND + lane] = myIdx;
        cand_pos[bg * NCAND + lane] = (covv > thr && cingv) ? 1.f : 0.f;
    }
}

// ---- K2: per-image resolution of multi-assigned priors ---------------------
// 896 threads: one candidate entry per thread (G*NCAND = 864).
__global__ __launch_bounds__(896) void k_resolve(const float4* __restrict__ priors,
                                                 const float4* __restrict__ gtb,
                                                 const float4* __restrict__ predb,
                                                 const int* __restrict__ gtl,
                                                 const int* __restrict__ cand_idx,
                                                 const float* __restrict__ cand_pos,
                                                 float4* __restrict__ rec) {
    __shared__ int cnt[P];           // 33.6 KB
    const int b = blockIdx.x;
    const int t = threadIdx.x;

    for (int i = t; i < P; i += 896) cnt[i] = 0;
    __syncthreads();

    const int base = b * G * NCAND;
    const int e = t;
    bool active = (e < G * NCAND) && (cand_pos[base + e] > 0.f);
    int p = 0;
    if (active) {
        p = cand_idx[base + e];
        atomicAdd(&cnt[p], 1);
    }
    __syncthreads();

    if (active) {
        int gi = e / NCAND;
        if (cnt[p] > 1) {
            // multi-assigned: argmax over ALL g of IoU(gt, prior[p]), tie -> first
            float4 pr = priors[p];
            float best = -1.f; gi = 0;
            for (int g2 = 0; g2 < G; ++g2) {
                float4 gt2 = gtb[b * G + g2];
                float ov = iou_prior(gt2.x, gt2.y, gt2.z, gt2.w, pr);
                if (ov > best) { best = ov; gi = g2; }
            }
            // duplicates at same p compute identical gi -> identical record (benign)
        }
        float4 gt = gtb[b * G + gi];
        float4 pd = predb[b * P + p];
        // reference stage-7 IoU: clipped areas, +1e-9 in denominator
        float ltx = fmaxf(gt.x, pd.x), lty = fmaxf(gt.y, pd.y);
        float rbx = fminf(gt.z, pd.z), rby = fminf(gt.w, pd.w);
        float iw = fmaxf(rbx - ltx, 0.f), ih = fmaxf(rby - lty, 0.f);
        float inter = iw * ih;
        float ag = fmaxf(gt.z - gt.x, 0.f) * fmaxf(gt.w - gt.y, 0.f);
        float ap = fmaxf(pd.z - pd.x, 0.f) * fmaxf(pd.w - pd.y, 0.f);
        float iou = inter / (ag + ap - inter + 1e-9f);
        int lab = gtl[b * G + gi];
        rec[b * P + p] = make_float4(1.f, (float)gi, iou, (float)lab);
    }
}

// ---- K3: fused dense outputs: scores (float4-coalesced) + labels/boxes/fgm -
__global__ __launch_bounds__(256) void k_out(const float4* __restrict__ rec,
                                             const float4* __restrict__ gtb,
                                             float* __restrict__ labels,
                                             float4* __restrict__ boxes,
                                             float4* __restrict__ scores,
                                             float* __restrict__ fgm) {
    int tid = blockIdx.x * 256 + threadIdx.x;   // over B*P*20, exact grid
    int bp = tid / 20;
    int q = tid - bp * 20;
    int b = bp / P;
    float4 r = rec[bp];
    bool fg = r.x > 0.f;
    float4 o = make_float4(0.f, 0.f, 0.f, 0.f);
    if (fg) {
        int lab = (int)r.w;
        int c0 = q * 4;
        if (lab >= c0 && lab < c0 + 4) {
            (&o.x)[lab - c0] = r.z;
        }
    }
    scores[tid] = o;
    if (q == 0) {
        int gi = fg ? (int)r.y : 0;             // background: argmax(all-zero) = 0
        labels[bp] = fg ? r.w : (float)NC;
        boxes[bp] = gtb[b * G + gi];
        fgm[bp] = fg ? 1.f : 0.f;
    }
}

extern "C" void kernel_launch(void* const* d_in, const int* in_sizes, int n_in,
                              void* d_out, int out_size, void* d_ws, size_t ws_size,
                              hipStream_t stream) {
    const float4* priors = (const float4*)d_in[0];
    // d_in[1] = num_level_priors (compile-time constants here)
    const int*    gtl    = (const int*)d_in[2];
    const float4* gtb    = (const float4*)d_in[3];
    const float*  flagv  = (const float*)d_in[4];
    const float4* predb  = (const float4*)d_in[5];

    char* wsb = (char*)d_ws;
    float4* rec      = (float4*)wsb;                                   // B*P*16 B
    int*    cand_idx = (int*)(wsb + (size_t)B * P * 16);               // B*G*27*4 B
    float*  cand_pos = (float*)(wsb + (size_t)B * P * 16 + (size_t)B * G * NCAND * 4);

    float*  out    = (float*)d_out;
    float*  labels = out;                                  // B*P
    float4* boxes  = (float4*)(out + B * P);               // B*P*4
    float4* scores = (float4*)(out + B * P + B * P * 4);   // B*P*80
    float*  fgm    = out + B * P + B * P * 4 + B * P * NC; // B*P

    hipLaunchKernelGGL(k_cand,    dim3(B * G),            dim3(64),  0, stream, priors, gtb, flagv, cand_idx, cand_pos, rec);
    hipLaunchKernelGGL(k_resolve, dim3(B),                dim3(896), 0, stream, priors, gtb, predb, gtl, cand_idx, cand_pos, rec);
    hipLaunchKernelGGL(k_out,     dim3(B * P * 20 / 256), dim3(256), 0, stream, rec, gtb, labels, boxes, scores, fgm);
}